// Round 5
// baseline (855.891 us; speedup 1.0000x reference)
//
#include <hip/hip_runtime.h>
#include <hip/hip_bf16.h>

// ---- problem constants ----
#define B_  4
#define T_  2048
#define C_  2048
#define H_  16
#define DH_ 128
#define MROWS (B_ * T_)          // 8192

typedef unsigned short bf16;     // raw bf16 bits
typedef __attribute__((ext_vector_type(8))) short bf16x8;   // MFMA A/B frag (8 bf16)
typedef __attribute__((ext_vector_type(4))) float f32x4;    // MFMA C/D frag

__device__ __forceinline__ float bf2f(bf16 h) {
    return __uint_as_float(((unsigned int)h) << 16);
}
__device__ __forceinline__ bf16 f2bf(float f) {
    unsigned int u = __float_as_uint(f);
    u = (u + 0x7fffu + ((u >> 16) & 1u)) >> 16;   // RNE
    return (bf16)u;
}

// async global->LDS, 16B per lane; LDS dest = wave-uniform base + lane*16 (m97-verified usage)
__device__ __forceinline__ void gld16(const bf16* g, bf16* l) {
    __builtin_amdgcn_global_load_lds(
        (const __attribute__((address_space(1))) unsigned int*)(const unsigned int*)g,
        (__attribute__((address_space(3))) unsigned int*)(unsigned int*)l,
        16, 0, 0);
}

// ---------------- kernel 0: fp32 -> bf16 weight conversion (one-shot, amortized 64x) ----------------
__global__ __launch_bounds__(256) void w2bf(const float* __restrict__ w, bf16* __restrict__ o) {
    const size_t i = ((size_t)blockIdx.x * 256 + threadIdx.x) * 8;
    float4 a = *(const float4*)(w + i);
    float4 b = *(const float4*)(w + i + 4);
    union { uint4 u; bf16 h[8]; } p;
    p.h[0] = f2bf(a.x); p.h[1] = f2bf(a.y); p.h[2] = f2bf(a.z); p.h[3] = f2bf(a.w);
    p.h[4] = f2bf(b.x); p.h[5] = f2bf(b.y); p.h[6] = f2bf(b.z); p.h[7] = f2bf(b.w);
    *(uint4*)(o + i) = p.u;
}

// ---------------- kernel 1: RMSNorm over C (fp32 in, bf16 out) ----------------
__global__ __launch_bounds__(256) void rmsnorm_x(const float* __restrict__ in,
                                                 bf16* __restrict__ outx) {
    const int row = blockIdx.x, tid = threadIdx.x;
    const size_t base = (size_t)row * C_ + tid * 8;
    float4 a = *(const float4*)(in + base);
    float4 b = *(const float4*)(in + base + 4);
    float f[8] = {a.x, a.y, a.z, a.w, b.x, b.y, b.z, b.w};
    float ss = 0.f;
#pragma unroll
    for (int i = 0; i < 8; ++i) ss += f[i] * f[i];
#pragma unroll
    for (int m = 32; m; m >>= 1) ss += __shfl_xor(ss, m, 64);
    __shared__ float red[4];
    if ((tid & 63) == 0) red[tid >> 6] = ss;
    __syncthreads();
    float tot = red[0] + red[1] + red[2] + red[3];
    float sc = rsqrtf(tot * (1.0f / (float)C_) + 1.1920929e-07f);
    union { uint4 u; bf16 h[8]; } o;
#pragma unroll
    for (int i = 0; i < 8; ++i) o.h[i] = f2bf(f[i] * sc);
    *(uint4*)(outx + base) = o.u;
}

// ---------------- GEMM: D[m][n] = sum_k A[m][k] * W[n][k], both bf16 ----------------
// Pure m97 structure: both operands staged via global_load_lds width=16, plain LDS layout.
// MODE 0: bf16 store. MODE 1: += fp32 residual, store FP32 (final output). MODE 2: bf16 V^T store.
template <int MODE>
__global__ __launch_bounds__(256, 2)
void gemm_bt(const bf16* __restrict__ A, const bf16* __restrict__ W,
             void* __restrict__ Dv, const float* __restrict__ Add) {
    __shared__ __align__(16) bf16 sA[128 * 64];
    __shared__ __align__(16) bf16 sB[128 * 64];
    const int tid = threadIdx.x;
    const int w = tid >> 6, L = tid & 63;
    const int lane15 = L & 15, quad = L >> 4;
    const int m0 = blockIdx.x * 128, n0 = blockIdx.y * 128;
    const int wm = w >> 1, wn = w & 1;

    // plain staging: slot -> row = slot>>3, chunk = slot&7 (no swizzle; gld16 needs linear dest)
    const bf16* aptr[4];
    const bf16* bptr[4];
#pragma unroll
    for (int it = 0; it < 4; ++it) {
        int slot = it * 256 + tid;
        int row = slot >> 3;
        int ch = slot & 7;
        aptr[it] = A + (size_t)(m0 + row) * C_ + ch * 8;
        bptr[it] = W + (size_t)(n0 + row) * C_ + ch * 8;
    }

    f32x4 acc[4][4] = {};
#pragma unroll 1
    for (int kt = 0; kt < C_ / 64; ++kt) {
        __syncthreads();
#pragma unroll
        for (int it = 0; it < 4; ++it) {
            gld16(aptr[it], sA + (size_t)(it * 256 + w * 64) * 8);
            aptr[it] += 64;
        }
#pragma unroll
        for (int it = 0; it < 4; ++it) {
            gld16(bptr[it], sB + (size_t)(it * 256 + w * 64) * 8);
            bptr[it] += 64;
        }
        __syncthreads();
#pragma unroll
        for (int ks = 0; ks < 2; ++ks) {
            bf16x8 af[4], bfr[4];
#pragma unroll
            for (int i = 0; i < 4; ++i) {
                int ar = wm * 64 + i * 16 + lane15;
                af[i]  = *(const bf16x8*)(sA + ar * 64 + (ks * 4 + quad) * 8);
                int br = wn * 64 + i * 16 + lane15;
                bfr[i] = *(const bf16x8*)(sB + br * 64 + (ks * 4 + quad) * 8);
            }
#pragma unroll
            for (int i = 0; i < 4; ++i)
#pragma unroll
                for (int j = 0; j < 4; ++j)
                    acc[i][j] = __builtin_amdgcn_mfma_f32_16x16x32_bf16(af[i], bfr[j], acc[i][j], 0, 0, 0);
        }
    }

    // epilogue
    if (MODE == 2) {
        bf16* D = (bf16*)Dv;
        // vt[((b*H + h)*DH + dh)*T + t], 4 consecutive t per lane -> 8B store
#pragma unroll
        for (int i = 0; i < 4; ++i) {
            int t0 = m0 + wm * 64 + i * 16 + quad * 4;
            int bidx = t0 >> 11, tin = t0 & (T_ - 1);
#pragma unroll
            for (int j = 0; j < 4; ++j) {
                int col = n0 + wn * 64 + j * 16 + lane15;
                int hh = col >> 7, dh = col & (DH_ - 1);
                unsigned int lo = (unsigned int)f2bf(acc[i][j][0]) | ((unsigned int)f2bf(acc[i][j][1]) << 16);
                unsigned int hi = (unsigned int)f2bf(acc[i][j][2]) | ((unsigned int)f2bf(acc[i][j][3]) << 16);
                uint2 val; val.x = lo; val.y = hi;
                *(uint2*)(D + ((size_t)((bidx * H_ + hh) * DH_ + dh)) * T_ + tin) = val;
            }
        }
    } else if (MODE == 1) {
        float* D = (float*)Dv;   // FINAL OUTPUT IS FP32
#pragma unroll
        for (int i = 0; i < 4; ++i)
#pragma unroll
            for (int j = 0; j < 4; ++j)
#pragma unroll
                for (int r = 0; r < 4; ++r) {
                    int row = m0 + wm * 64 + i * 16 + quad * 4 + r;
                    int col = n0 + wn * 64 + j * 16 + lane15;
                    D[(size_t)row * C_ + col] = acc[i][j][r] + Add[(size_t)row * C_ + col];
                }
    } else {
        bf16* D = (bf16*)Dv;
#pragma unroll
        for (int i = 0; i < 4; ++i)
#pragma unroll
            for (int j = 0; j < 4; ++j)
#pragma unroll
                for (int r = 0; r < 4; ++r) {
                    int row = m0 + wm * 64 + i * 16 + quad * 4 + r;
                    int col = n0 + wn * 64 + j * 16 + lane15;
                    D[(size_t)row * C_ + col] = f2bf(acc[i][j][r]);
                }
    }
}

// ---------------- kernel 3: per-head RMSNorm + RoPE (in place on q and k) ----------------
__global__ __launch_bounds__(256) void qknorm_rope(bf16* __restrict__ q, bf16* __restrict__ k) {
    const int bt = blockIdx.x;
    bf16* buf = blockIdx.y ? k : q;
    const int w = threadIdx.x >> 6, L = threadIdx.x & 63;
    const int t = bt & (T_ - 1);
    // inv_freq = 10000^(-L/64) in high precision; angle fp32 (matches np fp32 tables to ~1ulp)
    float inv = (float)exp2(-(double)L * 0.20762050593046006);
    float ang = (float)t * inv;
    float s, c;
    sincosf(ang, &s, &c);
#pragma unroll
    for (int hh = 0; hh < 4; ++hh) {
        int h = w * 4 + hh;
        bf16* p = buf + (size_t)bt * C_ + h * DH_;
        float x1 = bf2f(p[L]), x2 = bf2f(p[L + 64]);
        float ss = x1 * x1 + x2 * x2;
#pragma unroll
        for (int m = 32; m; m >>= 1) ss += __shfl_xor(ss, m, 64);
        float sc = rsqrtf(ss * (1.0f / (float)DH_) + 1.1920929e-07f);
        float y1 = (x1 * c + x2 * s) * sc;
        float y2 = (x2 * c - x1 * s) * sc;
        p[L]      = f2bf(y1);
        p[L + 64] = f2bf(y2);
    }
}

// ---------------- kernel 4: causal flash attention v4 ----------------
// KVBLK=64, 48 KB LDS (3 blocks/CU) + T14 async-STAGE split: tile jj+1 is loaded into
// REGISTERS right after tile jj becomes visible (HBM latency hides under jj's compute);
// the regs are ds_written to LDS at the top of iteration jj+1, so the inter-barrier
// window is just 8 ds_writes (R4 lesson: exposed staging between barriers cost +120us).
// Reg staging also lets the LDS write be swizzled directly; global reads stay linear.
// bh-grouped XCD swizzle: all 16 qt-tiles of one (b,h) pin to one XCD (fid&7 fixed)
// so K/V panels are reused within a single L2 (R4: FETCH grew 221->325 MB).
__global__ __launch_bounds__(256, 3)
void attn_fwd(const bf16* __restrict__ q, const bf16* __restrict__ k,
              const bf16* __restrict__ vt, bf16* __restrict__ y) {
    __shared__ __align__(16) bf16 sK[64 * 128];   // [kr][dh], swizzled
    __shared__ __align__(16) bf16 sV[128 * 64];   // [dh][kr], swizzled
    __shared__ __align__(16) bf16 sP[128 * 64];   // [qrow][kr], wave-local rows, swizzled
    const int tid = threadIdx.x;
    const int w = tid >> 6, L = tid & 63;
    const int lane15 = L & 15, quad = L >> 4;
    const float SCALE = 0.08838834764831845f;      // 1/sqrt(128)

    // bh-grouped XCD swizzle + LPT: fid = lo(3b XCD lane) | qtr(4b) | hi(3b)
    // bh = lo + 8*hi (fixed per XCD lane), qt = 15 - qtr (heavy-first in dispatch order)
    const int fid = (int)blockIdx.y * (int)gridDim.x + (int)blockIdx.x;
    const int bh = (fid & 7) + ((fid >> 7) << 3);
    const int qt = 15 - ((fid >> 3) & 15);
    const int b = bh >> 4, h = bh & 15;

    const bf16* kbase = k  + ((size_t)(b * T_)) * C_ + h * DH_;
    const bf16* vbase = vt + ((size_t)bh * DH_) * T_;

    // per-thread staging geometry (constant): K rows krow0+16*it, V rows vrow0+32*it
    const int kch = tid & 15, krow0 = tid >> 4;
    const int vch = tid & 7,  vrow0 = tid >> 3;
    const int kldsoff = krow0 * 128 + ((kch ^ (krow0 & 7)) << 3);   // +16*128 per it (16%8==0: xor const)
    const int vldsoff = vrow0 * 64  + ((vch ^ (vrow0 & 7)) << 3);   // +32*64 per it

    // Q fragments in registers: B-operand layout B[k=d][n=qrow]
    bf16x8 qf[2][4];
#pragma unroll
    for (int nt = 0; nt < 2; ++nt)
#pragma unroll
        for (int ks = 0; ks < 4; ++ks) {
            int qrow = qt * 128 + w * 32 + nt * 16 + lane15;
            qf[nt][ks] = *(const bf16x8*)(q + ((size_t)(b * T_ + qrow)) * C_ + h * DH_ + ks * 32 + quad * 8);
        }

    f32x4 o[2][8] = {};
    float m_i[2] = {-__builtin_inff(), -__builtin_inff()};
    float l_i[2] = {0.f, 0.f};

    const int jlast = 2 * qt + 1;

    uint4 kreg[4], vreg[4];
#define LOAD_KV(jj)                                                                      \
    do {                                                                                 \
        const int base_ = (jj) * 64;                                                     \
        _Pragma("unroll")                                                                \
        for (int it = 0; it < 4; ++it) {                                                 \
            kreg[it] = *(const uint4*)(kbase + (size_t)(base_ + krow0 + it * 16) * C_ + kch * 8); \
            vreg[it] = *(const uint4*)(vbase + (size_t)(vrow0 + it * 32) * T_ + base_ + vch * 8); \
        }                                                                                \
    } while (0)

    LOAD_KV(0);

    for (int jj = 0; jj <= jlast; ++jj) {
        __syncthreads();   // all reads of previous tile done
        // regs -> LDS (vmcnt satisfied long ago: loads issued a full compute phase back)
#pragma unroll
        for (int it = 0; it < 4; ++it) {
            *(uint4*)(sK + kldsoff + it * (16 * 128)) = kreg[it];
            *(uint4*)(sV + vldsoff + it * (32 * 64))  = vreg[it];
        }
        __syncthreads();   // tile visible
        if (jj < jlast) LOAD_KV(jj + 1);   // T14: issue next tile early; lands under compute

        const bool skip = (jj == jlast) && (w < 2);   // wave-uniform: fully-masked diagonal half
        if (!skip) {
            // S^T tile: rows kr (4 m-tiles of 16), cols qrow (2 n-tiles)
            f32x4 sc[4][2] = {};
            __builtin_amdgcn_s_setprio(1);
#pragma unroll
            for (int ks = 0; ks < 4; ++ks)
#pragma unroll
                for (int mt = 0; mt < 4; ++mt) {
                    int ar = mt * 16 + lane15;
                    bf16x8 a = *(const bf16x8*)(sK + ar * 128 + (((ks * 4 + quad) ^ (ar & 7)) << 3));
                    sc[mt][0] = __builtin_amdgcn_mfma_f32_16x16x32_bf16(a, qf[0][ks], sc[mt][0], 0, 0, 0);
                    sc[mt][1] = __builtin_amdgcn_mfma_f32_16x16x32_bf16(a, qf[1][ks], sc[mt][1], 0, 0, 0);
                }
            __builtin_amdgcn_s_setprio(0);

            // scale + causal mask (diagonal tiles only) + online softmax (stats per qrow)
            const bool diag = (jj == 2 * qt && w < 2) || (jj == jlast && w >= 2);
            float alpha[2];
            bool needv[2];
#pragma unroll
            for (int nt = 0; nt < 2; ++nt) {
                const int qr = qt * 128 + w * 32 + nt * 16 + lane15;
                float mx = -__builtin_inff();
#pragma unroll
                for (int mt = 0; mt < 4; ++mt)
#pragma unroll
                    for (int r = 0; r < 4; ++r) {
                        float v = sc[mt][nt][r] * SCALE;
                        if (diag) {
                            int kr = jj * 64 + mt * 16 + quad * 4 + r;
                            if (kr > qr) v = -__builtin_inff();
                        }
                        sc[mt][nt][r] = v;
                        mx = fmaxf(mx, v);
                    }
                mx = fmaxf(mx, __shfl_xor(mx, 16));
                mx = fmaxf(mx, __shfl_xor(mx, 32));
                // T13 defer-max: keep old max unless some row grew by > 8
                bool nd = __any(mx > m_i[nt] + 8.0f) != 0;
                float mn = nd ? fmaxf(m_i[nt], mx) : m_i[nt];
                alpha[nt] = nd ? __expf(m_i[nt] - mn) : 1.0f;
                needv[nt] = nd;
                float sum = 0.f;
#pragma unroll
                for (int mt = 0; mt < 4; ++mt)
#pragma unroll
                    for (int r = 0; r < 4; ++r) {
                        float p = __expf(sc[mt][nt][r] - mn);
                        sc[mt][nt][r] = p;
                        sum += p;
                    }
                sum += __shfl_xor(sum, 16);
                sum += __shfl_xor(sum, 32);
                l_i[nt] = l_i[nt] * alpha[nt] + sum;
                m_i[nt] = mn;
            }

            // write P (bf16) into wave-local sP rows, swizzled (chunk-granular XOR)
#pragma unroll
            for (int mt = 0; mt < 4; ++mt)
#pragma unroll
                for (int nt = 0; nt < 2; ++nt) {
                    int prow = w * 32 + nt * 16 + lane15;
                    int kr0 = mt * 16 + quad * 4;
                    int off = prow * 64 + ((((kr0 >> 3) ^ (prow & 7)) << 3) | (kr0 & 7));
                    unsigned int lo = (unsigned int)f2bf(sc[mt][nt][0]) | ((unsigned int)f2bf(sc[mt][nt][1]) << 16);
                    unsigned int hi = (unsigned int)f2bf(sc[mt][nt][2]) | ((unsigned int)f2bf(sc[mt][nt][3]) << 16);
                    uint2 val; val.x = lo; val.y = hi;
                    *(uint2*)(sP + off) = val;
                }

            // rescale O by alpha (broadcast from stats lane), skipped when deferred (alpha==1)
#pragma unroll
            for (int g = 0; g < 2; ++g)
                if (needv[g]) {
#pragma unroll
                    for (int r = 0; r < 4; ++r) {
                        float av = __shfl(alpha[g], quad * 4 + r, 64);
#pragma unroll
                        for (int d = 0; d < 8; ++d) o[g][d][r] *= av;
                    }
                }

            // O += P * V (P read is wave-local; per-wave DS ordering guarantees visibility)
            __builtin_amdgcn_s_setprio(1);
#pragma unroll
            for (int ks = 0; ks < 2; ++ks) {
                bf16x8 ap[2];
#pragma unroll
                for (int g = 0; g < 2; ++g) {
                    int pr = w * 32 + g * 16 + lane15;
                    ap[g] = *(const bf16x8*)(sP + pr * 64 + (((ks * 4 + quad) ^ (pr & 7)) << 3));
                }
#pragma unroll
                for (int d = 0; d < 8; ++d) {
                    int vr = d * 16 + lane15;
                    bf16x8 bv = *(const bf16x8*)(sV + vr * 64 + (((ks * 4 + quad) ^ (vr & 7)) << 3));
                    o[0][d] = __builtin_amdgcn_mfma_f32_16x16x32_bf16(ap[0], bv, o[0][d], 0, 0, 0);
                    o[1][d] = __builtin_amdgcn_mfma_f32_16x16x32_bf16(ap[1], bv, o[1][d], 0, 0, 0);
                }
            }
            __builtin_amdgcn_s_setprio(0);
        }
    }
#undef LOAD_KV

    // epilogue: divide by l, store y (bf16 scratch for proj GEMM)
    float rl[2] = {1.f / l_i[0], 1.f / l_i[1]};
#pragma unroll
    for (int g = 0; g < 2; ++g)
#pragma unroll
        for (int r = 0; r < 4; ++r) {
            float linv = __shfl(rl[g], quad * 4 + r, 64);
            int t = qt * 128 + w * 32 + g * 16 + quad * 4 + r;
#pragma unroll
            for (int d = 0; d < 8; ++d)
                y[((size_t)(b * T_ + t)) * C_ + h * DH_ + d * 16 + lane15] = f2bf(o[g][d][r] * linv);
        }
}

// ---------------- launch ----------------
// Inputs fp32, OUTPUT FP32 (64 MB). ws = 3 bf16 tensors (96 MB): x, q, vt.
// d_out doubles as scratch: [0,32MB) = kk (bf16 K), [32,56MB) = bf16 wq/wk/wv.
// wproj-bf16 is converted into the dead q region AFTER attn, so the final proj GEMM
// (which overwrites all of d_out with fp32) never races its own weight reads.
extern "C" void kernel_launch(void* const* d_in, const int* in_sizes, int n_in,
                              void* d_out, int out_size, void* d_ws, size_t ws_size,
                              hipStream_t stream) {
    const float* residual = (const float*)d_in[0];
    const float* wq    = (const float*)d_in[1];
    const float* wk    = (const float*)d_in[2];
    const float* wv    = (const float*)d_in[3];
    const float* wproj = (const float*)d_in[4];

    const size_t NE = (size_t)B_ * T_ * C_;   // 16,777,216
    const size_t WE = (size_t)C_ * C_;        // 4,194,304
    bf16* x  = (bf16*)d_ws;
    bf16* q  = x + NE;
    bf16* vt = q + NE;
    bf16* kk = (bf16*)d_out;                  // scratch inside fp32 out buffer
    bf16* wqb = kk + NE;                      // d_out + 32MB
    bf16* wkb = wqb + WE;
    bf16* wvb = wkb + WE;                     // ends at 56MB < 64MB
    bf16* y  = x;                             // x dead after v-GEMM; reuse for attention output
    bf16* wpb = q;                            // q dead after attn; reuse for bf16 wproj

    const dim3 gemm_grid(MROWS / 128, C_ / 128);
    const int wgrid = (int)(WE / (256 * 8));  // 2048 blocks

    w2bf<<<wgrid, 256, 0, stream>>>(wq, wqb);
    w2bf<<<wgrid, 256, 0, stream>>>(wk, wkb);
    w2bf<<<wgrid, 256, 0, stream>>>(wv, wvb);
    rmsnorm_x<<<MROWS, 256, 0, stream>>>(residual, x);
    gemm_bt<0><<<gemm_grid, 256, 0, stream>>>(x, wqb, q,  nullptr);
    gemm_bt<0><<<gemm_grid, 256, 0, stream>>>(x, wkb, kk, nullptr);
    gemm_bt<2><<<gemm_grid, 256, 0, stream>>>(x, wvb, vt, nullptr);
    qknorm_rope<<<dim3(MROWS, 2), 256, 0, stream>>>(q, kk);
    attn_fwd<<<dim3(T_ / 128, B_ * H_), 256, 0, stream>>>(q, kk, vt, y);
    w2bf<<<wgrid, 256, 0, stream>>>(wproj, wpb);
    gemm_bt<1><<<gemm_grid, 256, 0, stream>>>(y, wpb, d_out, residual);
}

// Round 6
// 797.867 us; speedup vs baseline: 1.0727x; 1.0727x over previous
//
#include <hip/hip_runtime.h>
#include <hip/hip_bf16.h>

// ---- problem constants ----
#define B_  4
#define T_  2048
#define C_  2048
#define H_  16
#define DH_ 128
#define MROWS (B_ * T_)          // 8192

typedef unsigned short bf16;     // raw bf16 bits
typedef __attribute__((ext_vector_type(8))) short bf16x8;   // MFMA A/B frag (8 bf16)
typedef __attribute__((ext_vector_type(4))) float f32x4;    // MFMA C/D frag

__device__ __forceinline__ float bf2f(bf16 h) {
    return __uint_as_float(((unsigned int)h) << 16);
}
__device__ __forceinline__ bf16 f2bf(float f) {
    unsigned int u = __float_as_uint(f);
    u = (u + 0x7fffu + ((u >> 16) & 1u)) >> 16;   // RNE
    return (bf16)u;
}

// XOR swizzle helper (element-offset form of byte^=((row&7)<<4)) for bank-conflict-free
// ds_read_b128 of row-major LDS tiles (G4 / T2).
__device__ __forceinline__ int swz8(int row, int col) {
    return col ^ ((row & 7) << 3);
}

// async global->LDS, 16B per lane; LDS dest = wave-uniform base + lane*16 (m97-verified usage)
__device__ __forceinline__ void gld16(const bf16* g, bf16* l) {
    __builtin_amdgcn_global_load_lds(
        (const __attribute__((address_space(1))) unsigned int*)(const unsigned int*)g,
        (__attribute__((address_space(3))) unsigned int*)(unsigned int*)l,
        16, 0, 0);
}

// ---------------- kernel 0: fp32 -> bf16 weight conversion (one-shot, amortized 64x) ----------------
__global__ __launch_bounds__(256) void w2bf(const float* __restrict__ w, bf16* __restrict__ o) {
    const size_t i = ((size_t)blockIdx.x * 256 + threadIdx.x) * 8;
    float4 a = *(const float4*)(w + i);
    float4 b = *(const float4*)(w + i + 4);
    union { uint4 u; bf16 h[8]; } p;
    p.h[0] = f2bf(a.x); p.h[1] = f2bf(a.y); p.h[2] = f2bf(a.z); p.h[3] = f2bf(a.w);
    p.h[4] = f2bf(b.x); p.h[5] = f2bf(b.y); p.h[6] = f2bf(b.z); p.h[7] = f2bf(b.w);
    *(uint4*)(o + i) = p.u;
}

// ---------------- kernel 1: RMSNorm over C (fp32 in, bf16 out) ----------------
__global__ __launch_bounds__(256) void rmsnorm_x(const float* __restrict__ in,
                                                 bf16* __restrict__ outx) {
    const int row = blockIdx.x, tid = threadIdx.x;
    const size_t base = (size_t)row * C_ + tid * 8;
    float4 a = *(const float4*)(in + base);
    float4 b = *(const float4*)(in + base + 4);
    float f[8] = {a.x, a.y, a.z, a.w, b.x, b.y, b.z, b.w};
    float ss = 0.f;
#pragma unroll
    for (int i = 0; i < 8; ++i) ss += f[i] * f[i];
#pragma unroll
    for (int m = 32; m; m >>= 1) ss += __shfl_xor(ss, m, 64);
    __shared__ float red[4];
    if ((tid & 63) == 0) red[tid >> 6] = ss;
    __syncthreads();
    float tot = red[0] + red[1] + red[2] + red[3];
    float sc = rsqrtf(tot * (1.0f / (float)C_) + 1.1920929e-07f);
    union { uint4 u; bf16 h[8]; } o;
#pragma unroll
    for (int i = 0; i < 8; ++i) o.h[i] = f2bf(f[i] * sc);
    *(uint4*)(outx + base) = o.u;
}

// ---------------- GEMM v2: 256x256 tile, BK=64, 8 waves, 8-phase interleave ----------------
// D[m][n] = sum_k A[m][k] * W[n][k], both bf16.
// T3+T4: double-buffered LDS (128 KB, 1 block/CU), staging of tile T+1 issued during
// phases 0-1 of tile T into the slot freed at the last boundary; ONE vmcnt(0)+barrier
// per K-tile (loads stay in flight across ~3 MFMA phases, never per-phase drains).
// T2: XOR-swizzled LDS reads + inverse-permuted global source (rule 21 both-sides).
// T5: setprio around each 16-MFMA cluster. Raw s_barrier between phases (no drain).
// MODE 0: bf16 store. MODE 1: += fp32 residual, store FP32. MODE 2: bf16 V^T store.
template <int MODE>
__global__ __launch_bounds__(512, 2)
void gemm_bt(const bf16* __restrict__ A, const bf16* __restrict__ W,
             void* __restrict__ Dv, const float* __restrict__ Add) {
    __shared__ __align__(16) bf16 sA[2][256 * 64];
    __shared__ __align__(16) bf16 sB[2][256 * 64];
    const int tid = threadIdx.x;
    const int wid = tid >> 6, L = tid & 63;
    const int lane15 = L & 15, quad = L >> 4;
    const int wm = wid >> 2, wn = wid & 3;            // 2 M-waves x 4 N-waves

    // bijective XCD swizzle (nwg=256, 256%8==0): XCD x owns logical ids x*32..x*32+31,
    // i.e. one full by-row -> B-panel reused 32x inside one L2.
    const int fid = (int)blockIdx.y * (int)gridDim.x + (int)blockIdx.x;
    const int bid = (fid & 7) * 32 + (fid >> 3);
    const int bx = bid & 31, by = bid >> 5;
    const int m0 = bx * 256, n0 = by * 256;

    // staging geometry: half-tile = 128 rows x 64 cols = 16 KB = 512 thr x 2 gld16.
    // slot = j*512+tid -> row = slot>>3, chunk = slot&7; global chunk inverse-swizzled.
    int st_row[2], st_ch[2];
#pragma unroll
    for (int j = 0; j < 2; ++j) {
        int slot = j * 512 + tid;
        st_row[j] = slot >> 3;
        st_ch[j]  = ((slot & 7) ^ (st_row[j] & 7)) << 3;
    }
    const int ldsoff0 = (0 * 512 + wid * 64) * 8;
    const int ldsoff1 = (1 * 512 + wid * 64) * 8;

    // stage half c (0:A0 1:A1 2:B0 3:B1) of K-tile Tn into slot Tn&1
#define STAGE_HALF(Tn, c)                                                              \
    do {                                                                               \
        const bf16* gb = (c) < 2 ? (A + (size_t)(m0 + (c) * 128) * C_)                 \
                                 : (W + (size_t)(n0 + ((c) - 2) * 128) * C_);          \
        bf16* lb = ((c) < 2 ? &sA[(Tn) & 1][0] : &sB[(Tn) & 1][0]) + ((c) & 1) * (128 * 64); \
        gld16(gb + (size_t)st_row[0] * C_ + (Tn) * 64 + st_ch[0], lb + ldsoff0);       \
        gld16(gb + (size_t)st_row[1] * C_ + (Tn) * 64 + st_ch[1], lb + ldsoff1);       \
    } while (0)

    f32x4 acc[8][4] = {};
    const int NT = C_ / 64;   // 32 K-tiles

    // prologue: stage tile 0, drain, barrier
#pragma unroll
    for (int c = 0; c < 4; ++c) STAGE_HALF(0, c);
    asm volatile("s_waitcnt vmcnt(0)" ::: "memory");
    __builtin_amdgcn_s_barrier();

    bf16x8 af[4][2];
#pragma unroll 1
    for (int T = 0; T < NT; ++T) {
        const int cur = T & 1;
        const bf16* sAc = &sA[cur][0];
        const bf16* sBc = &sB[cur][0];
#pragma unroll
        for (int c = 0; c < 4; ++c) {          // 4 quadrant-phases per K-tile
            const int mh = c >> 1, nl = c & 1;
            // staging of next tile: halves 0-1 in phase 0, halves 2-3 in phase 1
            if (T + 1 < NT) {
                if (c == 0) { STAGE_HALF(T + 1, 0); STAGE_HALF(T + 1, 1); }
                else if (c == 1) { STAGE_HALF(T + 1, 2); STAGE_HALF(T + 1, 3); }
            }
            // ds-reads: A-frags only when mh changes (phases 0,2), B-frags every phase
            if (nl == 0) {
#pragma unroll
                for (int a = 0; a < 4; ++a) {
                    int ar = wm * 128 + (mh * 4 + a) * 16 + lane15;
#pragma unroll
                    for (int kk = 0; kk < 2; ++kk)
                        af[a][kk] = *(const bf16x8*)(sAc + ar * 64 + swz8(ar, (kk * 4 + quad) * 8));
                }
            }
            bf16x8 bfr[2][2];
#pragma unroll
            for (int nb = 0; nb < 2; ++nb) {
                int br = wn * 64 + (nl * 2 + nb) * 16 + lane15;
#pragma unroll
                for (int kk = 0; kk < 2; ++kk)
                    bfr[nb][kk] = *(const bf16x8*)(sBc + br * 64 + swz8(br, (kk * 4 + quad) * 8));
            }
            __builtin_amdgcn_s_setprio(1);
#pragma unroll
            for (int kk = 0; kk < 2; ++kk)
#pragma unroll
                for (int a = 0; a < 4; ++a)
#pragma unroll
                    for (int nb = 0; nb < 2; ++nb)
                        acc[mh * 4 + a][nl * 2 + nb] = __builtin_amdgcn_mfma_f32_16x16x32_bf16(
                            af[a][kk], bfr[nb][kk], acc[mh * 4 + a][nl * 2 + nb], 0, 0, 0);
            __builtin_amdgcn_s_setprio(0);
            if (c < 3) {
                __builtin_amdgcn_s_barrier();          // phase lockstep, no drain
            } else {
                asm volatile("s_waitcnt vmcnt(0)" ::: "memory");   // next tile landed
                __builtin_amdgcn_s_barrier();                       // + slot freed
            }
        }
    }
#undef STAGE_HALF

    // epilogue: rows = m0 + wm*128 + mi*16 + quad*4 + r ; cols = n0 + wn*64 + nj*16 + lane15
    if (MODE == 2) {
        bf16* D = (bf16*)Dv;
#pragma unroll
        for (int mi = 0; mi < 8; ++mi) {
            int t0 = m0 + wm * 128 + mi * 16 + quad * 4;
            int bidx = t0 >> 11, tin = t0 & (T_ - 1);
#pragma unroll
            for (int nj = 0; nj < 4; ++nj) {
                int col = n0 + wn * 64 + nj * 16 + lane15;
                int hh = col >> 7, dh = col & (DH_ - 1);
                unsigned int lo = (unsigned int)f2bf(acc[mi][nj][0]) | ((unsigned int)f2bf(acc[mi][nj][1]) << 16);
                unsigned int hi = (unsigned int)f2bf(acc[mi][nj][2]) | ((unsigned int)f2bf(acc[mi][nj][3]) << 16);
                uint2 val; val.x = lo; val.y = hi;
                *(uint2*)(D + ((size_t)((bidx * H_ + hh) * DH_ + dh)) * T_ + tin) = val;
            }
        }
    } else if (MODE == 1) {
        float* D = (float*)Dv;   // FINAL OUTPUT IS FP32
#pragma unroll
        for (int mi = 0; mi < 8; ++mi)
#pragma unroll
            for (int nj = 0; nj < 4; ++nj)
#pragma unroll
                for (int r = 0; r < 4; ++r) {
                    int row = m0 + wm * 128 + mi * 16 + quad * 4 + r;
                    int col = n0 + wn * 64 + nj * 16 + lane15;
                    D[(size_t)row * C_ + col] = acc[mi][nj][r] + Add[(size_t)row * C_ + col];
                }
    } else {
        bf16* D = (bf16*)Dv;
#pragma unroll
        for (int mi = 0; mi < 8; ++mi)
#pragma unroll
            for (int nj = 0; nj < 4; ++nj)
#pragma unroll
                for (int r = 0; r < 4; ++r) {
                    int row = m0 + wm * 128 + mi * 16 + quad * 4 + r;
                    int col = n0 + wn * 64 + nj * 16 + lane15;
                    D[(size_t)row * C_ + col] = f2bf(acc[mi][nj][r]);
                }
    }
}

// ---------------- kernel 3: per-head RMSNorm + RoPE (in place on q and k) ----------------
__global__ __launch_bounds__(256) void qknorm_rope(bf16* __restrict__ q, bf16* __restrict__ k) {
    const int bt = blockIdx.x;
    bf16* buf = blockIdx.y ? k : q;
    const int w = threadIdx.x >> 6, L = threadIdx.x & 63;
    const int t = bt & (T_ - 1);
    // inv_freq = 10000^(-L/64) in high precision; angle fp32 (matches np fp32 tables to ~1ulp)
    float inv = (float)exp2(-(double)L * 0.20762050593046006);
    float ang = (float)t * inv;
    float s, c;
    sincosf(ang, &s, &c);
#pragma unroll
    for (int hh = 0; hh < 4; ++hh) {
        int h = w * 4 + hh;
        bf16* p = buf + (size_t)bt * C_ + h * DH_;
        float x1 = bf2f(p[L]), x2 = bf2f(p[L + 64]);
        float ss = x1 * x1 + x2 * x2;
#pragma unroll
        for (int m = 32; m; m >>= 1) ss += __shfl_xor(ss, m, 64);
        float sc = rsqrtf(ss * (1.0f / (float)DH_) + 1.1920929e-07f);
        float y1 = (x1 * c + x2 * s) * sc;
        float y2 = (x2 * c - x1 * s) * sc;
        p[L]      = f2bf(y1);
        p[L + 64] = f2bf(y2);
    }
}

// ---------------- kernel 4: causal flash attention (R1/R2 version, measured 237us) ----------------
__global__ __launch_bounds__(256, 2)
void attn_fwd(const bf16* __restrict__ q, const bf16* __restrict__ k,
              const bf16* __restrict__ vt, bf16* __restrict__ y) {
    __shared__ __align__(16) bf16 sKP[128 * 128];  // K tile, later reused for P
    __shared__ __align__(16) bf16 sV[128 * 128];   // Vt tile [dh][kr]
    const int qt = blockIdx.x, bh = blockIdx.y;
    const int b = bh >> 4, h = bh & 15;
    const int tid = threadIdx.x;
    const int w = tid >> 6, L = tid & 63;
    const int lane15 = L & 15, quad = L >> 4;
    const float SCALE = 0.08838834764831845f;      // 1/sqrt(128)

    // Q fragments in registers: B-operand layout B[k=d][n=qrow]
    bf16x8 qf[2][4];
#pragma unroll
    for (int nt = 0; nt < 2; ++nt)
#pragma unroll
        for (int ks = 0; ks < 4; ++ks) {
            int qrow = qt * 128 + w * 32 + nt * 16 + lane15;
            qf[nt][ks] = *(const bf16x8*)(q + ((size_t)(b * T_ + qrow)) * C_ + h * DH_ + ks * 32 + quad * 8);
        }

    f32x4 o[2][8] = {};
    float m_i[2] = {-__builtin_inff(), -__builtin_inff()};
    float l_i[2] = {0.f, 0.f};

    for (int j = 0; j <= qt; ++j) {
        __syncthreads();   // prior iteration's P/V reads done
        {
            const bf16* kb = k  + ((size_t)(b * T_ + j * 128)) * C_ + h * DH_;
            const bf16* vb = vt + ((size_t)bh * DH_) * T_ + j * 128;
#pragma unroll
            for (int it = 0; it < 8; ++it) {
                int slot = it * 256 + tid;
                int row = slot >> 4;
                int ch = slot & 15;
                bf16x8 kv = *(const bf16x8*)(kb + (size_t)row * C_ + ch * 8);
                bf16x8 vv = *(const bf16x8*)(vb + (size_t)row * T_ + ch * 8);
                *(bf16x8*)(sKP + row * 128 + swz8(row, ch * 8)) = kv;
                *(bf16x8*)(sV  + row * 128 + swz8(row, ch * 8)) = vv;
            }
        }
        __syncthreads();

        // S^T: rows = kr (8 m-tiles), cols = qrow (2 n-tiles)
        f32x4 sc[8][2] = {};
#pragma unroll
        for (int ks = 0; ks < 4; ++ks)
#pragma unroll
            for (int mt = 0; mt < 8; ++mt) {
                int ar = mt * 16 + lane15;
                bf16x8 a = *(const bf16x8*)(sKP + ar * 128 + swz8(ar, (ks * 4 + quad) * 8));
                sc[mt][0] = __builtin_amdgcn_mfma_f32_16x16x32_bf16(a, qf[0][ks], sc[mt][0], 0, 0, 0);
                sc[mt][1] = __builtin_amdgcn_mfma_f32_16x16x32_bf16(a, qf[1][ks], sc[mt][1], 0, 0, 0);
            }

        // scale + causal mask + online softmax (stats per qrow = lane&15)
        float alpha[2];
#pragma unroll
        for (int nt = 0; nt < 2; ++nt) {
            const int qr = qt * 128 + w * 32 + nt * 16 + lane15;
            float mx = -__builtin_inff();
#pragma unroll
            for (int mt = 0; mt < 8; ++mt)
#pragma unroll
                for (int r = 0; r < 4; ++r) {
                    float v = sc[mt][nt][r] * SCALE;
                    if (j == qt) {
                        int kr = j * 128 + mt * 16 + quad * 4 + r;
                        if (kr > qr) v = -__builtin_inff();
                    }
                    sc[mt][nt][r] = v;
                    mx = fmaxf(mx, v);
                }
            mx = fmaxf(mx, __shfl_xor(mx, 16));
            mx = fmaxf(mx, __shfl_xor(mx, 32));
            float mn = fmaxf(m_i[nt], mx);
            alpha[nt] = __expf(m_i[nt] - mn);
            float sum = 0.f;
#pragma unroll
            for (int mt = 0; mt < 8; ++mt)
#pragma unroll
                for (int r = 0; r < 4; ++r) {
                    float p = __expf(sc[mt][nt][r] - mn);
                    sc[mt][nt][r] = p;
                    sum += p;
                }
            sum += __shfl_xor(sum, 16);
            sum += __shfl_xor(sum, 32);
            l_i[nt] = l_i[nt] * alpha[nt] + sum;
            m_i[nt] = mn;
        }

        __syncthreads();   // all waves done reading K region -> safe to overwrite with P

        // write P (bf16) into sKP in A-operand layout [qrow][kr], swizzled, b64 packed
#pragma unroll
        for (int mt = 0; mt < 8; ++mt)
#pragma unroll
            for (int nt = 0; nt < 2; ++nt) {
                int prow = w * 32 + nt * 16 + lane15;
                int kr0 = mt * 16 + quad * 4;
                int off = prow * 128 + swz8(prow, kr0);
                unsigned int lo = (unsigned int)f2bf(sc[mt][nt][0]) | ((unsigned int)f2bf(sc[mt][nt][1]) << 16);
                unsigned int hi = (unsigned int)f2bf(sc[mt][nt][2]) | ((unsigned int)f2bf(sc[mt][nt][3]) << 16);
                uint2 val; val.x = lo; val.y = hi;
                *(uint2*)(sKP + off) = val;
            }

        // rescale O by alpha (broadcast from stats lane)
#pragma unroll
        for (int mt = 0; mt < 2; ++mt)
#pragma unroll
            for (int r = 0; r < 4; ++r) {
                float av = __shfl(alpha[mt], quad * 4 + r, 64);
#pragma unroll
                for (int d = 0; d < 8; ++d) o[mt][d][r] *= av;
            }

        __syncthreads();   // P visible

        // O += P * V
#pragma unroll
        for (int ks = 0; ks < 4; ++ks) {
            bf16x8 ap[2];
#pragma unroll
            for (int mt = 0; mt < 2; ++mt) {
                int pr = w * 32 + mt * 16 + lane15;
                ap[mt] = *(const bf16x8*)(sKP + pr * 128 + swz8(pr, (ks * 4 + quad) * 8));
            }
#pragma unroll
            for (int d = 0; d < 8; ++d) {
                int vr = d * 16 + lane15;
                bf16x8 bv = *(const bf16x8*)(sV + vr * 128 + swz8(vr, (ks * 4 + quad) * 8));
                o[0][d] = __builtin_amdgcn_mfma_f32_16x16x32_bf16(ap[0], bv, o[0][d], 0, 0, 0);
                o[1][d] = __builtin_amdgcn_mfma_f32_16x16x32_bf16(ap[1], bv, o[1][d], 0, 0, 0);
            }
        }
    }

    // epilogue: divide by l, store y (bf16 scratch for proj GEMM)
    float rl[2] = {1.f / l_i[0], 1.f / l_i[1]};
#pragma unroll
    for (int mt = 0; mt < 2; ++mt)
#pragma unroll
        for (int r = 0; r < 4; ++r) {
            float linv = __shfl(rl[mt], quad * 4 + r, 64);
            int t = qt * 128 + w * 32 + mt * 16 + quad * 4 + r;
#pragma unroll
            for (int d = 0; d < 8; ++d)
                y[((size_t)(b * T_ + t)) * C_ + h * DH_ + d * 16 + lane15] = f2bf(o[mt][d][r] * linv);
        }
}

// ---------------- launch ----------------
// Inputs fp32, OUTPUT FP32 (64 MB). ws = 3 bf16 tensors (96 MB): x, q, vt.
// d_out doubles as scratch: [0,32MB) = kk (bf16 K), [32,56MB) = bf16 wq/wk/wv.
// wproj-bf16 is converted into the dead q region AFTER attn, so the final proj GEMM
// (which overwrites all of d_out with fp32) never races its own weight reads.
extern "C" void kernel_launch(void* const* d_in, const int* in_sizes, int n_in,
                              void* d_out, int out_size, void* d_ws, size_t ws_size,
                              hipStream_t stream) {
    const float* residual = (const float*)d_in[0];
    const float* wq    = (const float*)d_in[1];
    const float* wk    = (const float*)d_in[2];
    const float* wv    = (const float*)d_in[3];
    const float* wproj = (const float*)d_in[4];

    const size_t NE = (size_t)B_ * T_ * C_;   // 16,777,216
    const size_t WE = (size_t)C_ * C_;        // 4,194,304
    bf16* x  = (bf16*)d_ws;
    bf16* q  = x + NE;
    bf16* vt = q + NE;
    bf16* kk = (bf16*)d_out;                  // scratch inside fp32 out buffer
    bf16* wqb = kk + NE;                      // d_out + 32MB
    bf16* wkb = wqb + WE;
    bf16* wvb = wkb + WE;                     // ends at 56MB < 64MB
    bf16* y  = x;                             // x dead after v-GEMM; reuse for attention output
    bf16* wpb = q;                            // q dead after attn; reuse for bf16 wproj

    const dim3 gemm_grid(MROWS / 256, C_ / 256);   // 32 x 8 = 256 blocks, 1/CU
    const int wgrid = (int)(WE / (256 * 8));  // 2048 blocks

    w2bf<<<wgrid, 256, 0, stream>>>(wq, wqb);
    w2bf<<<wgrid, 256, 0, stream>>>(wk, wkb);
    w2bf<<<wgrid, 256, 0, stream>>>(wv, wvb);
    rmsnorm_x<<<MROWS, 256, 0, stream>>>(residual, x);
    gemm_bt<0><<<gemm_grid, 512, 0, stream>>>(x, wqb, q,  nullptr);
    gemm_bt<0><<<gemm_grid, 512, 0, stream>>>(x, wkb, kk, nullptr);
    gemm_bt<2><<<gemm_grid, 512, 0, stream>>>(x, wvb, vt, nullptr);
    qknorm_rope<<<dim3(MROWS, 2), 256, 0, stream>>>(q, kk);
    attn_fwd<<<dim3(T_ / 128, B_ * H_), 256, 0, stream>>>(q, kk, vt, y);
    w2bf<<<wgrid, 256, 0, stream>>>(wproj, wpb);
    gemm_bt<1><<<gemm_grid, 512, 0, stream>>>(y, wpb, d_out, residual);
}

// Round 8
// 682.801 us; speedup vs baseline: 1.2535x; 1.1685x over previous
//
#include <hip/hip_runtime.h>
#include <hip/hip_bf16.h>

// ---- problem constants ----
#define B_  4
#define T_  2048
#define C_  2048
#define H_  16
#define DH_ 128
#define MROWS (B_ * T_)          // 8192

typedef unsigned short bf16;     // raw bf16 bits
typedef __attribute__((ext_vector_type(8))) short bf16x8;   // MFMA A/B frag (8 bf16)
typedef __attribute__((ext_vector_type(4))) float f32x4;    // MFMA C/D frag

__device__ __forceinline__ float bf2f(bf16 h) {
    return __uint_as_float(((unsigned int)h) << 16);
}
__device__ __forceinline__ bf16 f2bf(float f) {
    unsigned int u = __float_as_uint(f);
    u = (u + 0x7fffu + ((u >> 16) & 1u)) >> 16;   // RNE
    return (bf16)u;
}

// XOR swizzle for [row][128] bf16 LDS tiles (element-offset form of byte^=((row&7)<<4)).
// Breaks the 16-lane same-bank pattern of stride-256B fragment reads (G4 / T2, m214 +89%).
__device__ __forceinline__ int swz8(int row, int col) {
    return col ^ ((row & 7) << 3);
}

// async global->LDS, 16B per lane; LDS dest = wave-uniform base + lane*16 (m97-verified usage)
__device__ __forceinline__ void gld16(const bf16* g, bf16* l) {
    __builtin_amdgcn_global_load_lds(
        (const __attribute__((address_space(1))) unsigned int*)(const unsigned int*)g,
        (__attribute__((address_space(3))) unsigned int*)(unsigned int*)l,
        16, 0, 0);
}

// ---------------- kernel 0: fp32 -> bf16 weight conversion (one-shot, amortized 64x) ----------------
__global__ __launch_bounds__(256) void w2bf(const float* __restrict__ w, bf16* __restrict__ o) {
    const size_t i = ((size_t)blockIdx.x * 256 + threadIdx.x) * 8;
    float4 a = *(const float4*)(w + i);
    float4 b = *(const float4*)(w + i + 4);
    union { uint4 u; bf16 h[8]; } p;
    p.h[0] = f2bf(a.x); p.h[1] = f2bf(a.y); p.h[2] = f2bf(a.z); p.h[3] = f2bf(a.w);
    p.h[4] = f2bf(b.x); p.h[5] = f2bf(b.y); p.h[6] = f2bf(b.z); p.h[7] = f2bf(b.w);
    *(uint4*)(o + i) = p.u;
}

// ---------------- kernel 1: RMSNorm over C (fp32 in, bf16 out) ----------------
__global__ __launch_bounds__(256) void rmsnorm_x(const float* __restrict__ in,
                                                 bf16* __restrict__ outx) {
    const int row = blockIdx.x, tid = threadIdx.x;
    const size_t base = (size_t)row * C_ + tid * 8;
    float4 a = *(const float4*)(in + base);
    float4 b = *(const float4*)(in + base + 4);
    float f[8] = {a.x, a.y, a.z, a.w, b.x, b.y, b.z, b.w};
    float ss = 0.f;
#pragma unroll
    for (int i = 0; i < 8; ++i) ss += f[i] * f[i];
#pragma unroll
    for (int m = 32; m; m >>= 1) ss += __shfl_xor(ss, m, 64);
    __shared__ float red[4];
    if ((tid & 63) == 0) red[tid >> 6] = ss;
    __syncthreads();
    float tot = red[0] + red[1] + red[2] + red[3];
    float sc = rsqrtf(tot * (1.0f / (float)C_) + 1.1920929e-07f);
    union { uint4 u; bf16 h[8]; } o;
#pragma unroll
    for (int i = 0; i < 8; ++i) o.h[i] = f2bf(f[i] * sc);
    *(uint4*)(outx + base) = o.u;
}

// ---------------- fused QKV GEMM: m97 structure, A staged once, 3 B-matrices ----------------
// q[m][n] = sum_k x[m][k] wq[n][k]; same for k (-> kk) and v (-> vt transposed store).
// LDS 64 KB -> 2 blocks/CU (same as m97). acc = 3 x 4x4 f32x4 = 192 VGPR; (256,2) caps 256.
__global__ __launch_bounds__(256, 2)
void gemm_qkv(const bf16* __restrict__ A,
              const bf16* __restrict__ Wq, const bf16* __restrict__ Wk, const bf16* __restrict__ Wv,
              bf16* __restrict__ Dq, bf16* __restrict__ Dk, bf16* __restrict__ Dvt) {
    __shared__ __align__(16) bf16 sA[128 * 64];
    __shared__ __align__(16) bf16 sB[3][128 * 64];
    const int tid = threadIdx.x;
    const int w = tid >> 6, L = tid & 63;
    const int lane15 = L & 15, quad = L >> 4;
    const int m0 = blockIdx.x * 128, n0 = blockIdx.y * 128;
    const int wm = w >> 1, wn = w & 1;

    const bf16* aptr[4];
    const bf16* bptr[3][4];
#pragma unroll
    for (int it = 0; it < 4; ++it) {
        int slot = it * 256 + tid;
        int row = slot >> 3;
        int ch = slot & 7;
        aptr[it] = A + (size_t)(m0 + row) * C_ + ch * 8;
        bptr[0][it] = Wq + (size_t)(n0 + row) * C_ + ch * 8;
        bptr[1][it] = Wk + (size_t)(n0 + row) * C_ + ch * 8;
        bptr[2][it] = Wv + (size_t)(n0 + row) * C_ + ch * 8;
    }

    f32x4 accq[4][4] = {}, acck[4][4] = {}, accv[4][4] = {};
#pragma unroll 1
    for (int kt = 0; kt < C_ / 64; ++kt) {
        __syncthreads();
#pragma unroll
        for (int it = 0; it < 4; ++it) {
            gld16(aptr[it], sA + (size_t)(it * 256 + w * 64) * 8);
            aptr[it] += 64;
        }
#pragma unroll
        for (int m = 0; m < 3; ++m)
#pragma unroll
            for (int it = 0; it < 4; ++it) {
                gld16(bptr[m][it], sB[m] + (size_t)(it * 256 + w * 64) * 8);
                bptr[m][it] += 64;
            }
        __syncthreads();
#pragma unroll
        for (int ks = 0; ks < 2; ++ks) {
            bf16x8 af[4];
#pragma unroll
            for (int i = 0; i < 4; ++i) {
                int ar = wm * 64 + i * 16 + lane15;
                af[i] = *(const bf16x8*)(sA + ar * 64 + (ks * 4 + quad) * 8);
            }
            // matrix 0: q
            {
                bf16x8 bfr[4];
#pragma unroll
                for (int i = 0; i < 4; ++i) {
                    int br = wn * 64 + i * 16 + lane15;
                    bfr[i] = *(const bf16x8*)(sB[0] + br * 64 + (ks * 4 + quad) * 8);
                }
#pragma unroll
                for (int i = 0; i < 4; ++i)
#pragma unroll
                    for (int j = 0; j < 4; ++j)
                        accq[i][j] = __builtin_amdgcn_mfma_f32_16x16x32_bf16(af[i], bfr[j], accq[i][j], 0, 0, 0);
            }
            // matrix 1: k
            {
                bf16x8 bfr[4];
#pragma unroll
                for (int i = 0; i < 4; ++i) {
                    int br = wn * 64 + i * 16 + lane15;
                    bfr[i] = *(const bf16x8*)(sB[1] + br * 64 + (ks * 4 + quad) * 8);
                }
#pragma unroll
                for (int i = 0; i < 4; ++i)
#pragma unroll
                    for (int j = 0; j < 4; ++j)
                        acck[i][j] = __builtin_amdgcn_mfma_f32_16x16x32_bf16(af[i], bfr[j], acck[i][j], 0, 0, 0);
            }
            // matrix 2: v
            {
                bf16x8 bfr[4];
#pragma unroll
                for (int i = 0; i < 4; ++i) {
                    int br = wn * 64 + i * 16 + lane15;
                    bfr[i] = *(const bf16x8*)(sB[2] + br * 64 + (ks * 4 + quad) * 8);
                }
#pragma unroll
                for (int i = 0; i < 4; ++i)
#pragma unroll
                    for (int j = 0; j < 4; ++j)
                        accv[i][j] = __builtin_amdgcn_mfma_f32_16x16x32_bf16(af[i], bfr[j], accv[i][j], 0, 0, 0);
            }
        }
    }

    // epilogues
    // q, k: row-major bf16
#pragma unroll
    for (int i = 0; i < 4; ++i)
#pragma unroll
        for (int j = 0; j < 4; ++j)
#pragma unroll
            for (int r = 0; r < 4; ++r) {
                int row = m0 + wm * 64 + i * 16 + quad * 4 + r;
                int col = n0 + wn * 64 + j * 16 + lane15;
                Dq[(size_t)row * C_ + col] = f2bf(accq[i][j][r]);
                Dk[(size_t)row * C_ + col] = f2bf(acck[i][j][r]);
            }
    // v: transposed store vt[((b*H + h)*DH + dh)*T + t]
#pragma unroll
    for (int i = 0; i < 4; ++i) {
        int t0 = m0 + wm * 64 + i * 16 + quad * 4;
        int bidx = t0 >> 11, tin = t0 & (T_ - 1);
#pragma unroll
        for (int j = 0; j < 4; ++j) {
            int col = n0 + wn * 64 + j * 16 + lane15;
            int hh = col >> 7, dh = col & (DH_ - 1);
            unsigned int lo = (unsigned int)f2bf(accv[i][j][0]) | ((unsigned int)f2bf(accv[i][j][1]) << 16);
            unsigned int hi = (unsigned int)f2bf(accv[i][j][2]) | ((unsigned int)f2bf(accv[i][j][3]) << 16);
            uint2 val; val.x = lo; val.y = hi;
            *(uint2*)(Dvt + ((size_t)((bidx * H_ + hh) * DH_ + dh)) * T_ + tin) = val;
        }
    }
}

// ---------------- proj GEMM: m97 structure (R2-verified, ~104us) ----------------
// D[m][n] = sum_k A[m][k] * W[n][k] + Add, fp32 out.
__global__ __launch_bounds__(256, 2)
void gemm_proj(const bf16* __restrict__ A, const bf16* __restrict__ W,
               float* __restrict__ D, const float* __restrict__ Add) {
    __shared__ __align__(16) bf16 sA[128 * 64];
    __shared__ __align__(16) bf16 sB[128 * 64];
    const int tid = threadIdx.x;
    const int w = tid >> 6, L = tid & 63;
    const int lane15 = L & 15, quad = L >> 4;
    const int m0 = blockIdx.x * 128, n0 = blockIdx.y * 128;
    const int wm = w >> 1, wn = w & 1;

    const bf16* aptr[4];
    const bf16* bptr[4];
#pragma unroll
    for (int it = 0; it < 4; ++it) {
        int slot = it * 256 + tid;
        int row = slot >> 3;
        int ch = slot & 7;
        aptr[it] = A + (size_t)(m0 + row) * C_ + ch * 8;
        bptr[it] = W + (size_t)(n0 + row) * C_ + ch * 8;
    }

    f32x4 acc[4][4] = {};
#pragma unroll 1
    for (int kt = 0; kt < C_ / 64; ++kt) {
        __syncthreads();
#pragma unroll
        for (int it = 0; it < 4; ++it) {
            gld16(aptr[it], sA + (size_t)(it * 256 + w * 64) * 8);
            aptr[it] += 64;
        }
#pragma unroll
        for (int it = 0; it < 4; ++it) {
            gld16(bptr[it], sB + (size_t)(it * 256 + w * 64) * 8);
            bptr[it] += 64;
        }
        __syncthreads();
#pragma unroll
        for (int ks = 0; ks < 2; ++ks) {
            bf16x8 af[4], bfr[4];
#pragma unroll
            for (int i = 0; i < 4; ++i) {
                int ar = wm * 64 + i * 16 + lane15;
                af[i]  = *(const bf16x8*)(sA + ar * 64 + (ks * 4 + quad) * 8);
                int br = wn * 64 + i * 16 + lane15;
                bfr[i] = *(const bf16x8*)(sB + br * 64 + (ks * 4 + quad) * 8);
            }
#pragma unroll
            for (int i = 0; i < 4; ++i)
#pragma unroll
                for (int j = 0; j < 4; ++j)
                    acc[i][j] = __builtin_amdgcn_mfma_f32_16x16x32_bf16(af[i], bfr[j], acc[i][j], 0, 0, 0);
        }
    }

#pragma unroll
    for (int i = 0; i < 4; ++i)
#pragma unroll
        for (int j = 0; j < 4; ++j)
#pragma unroll
            for (int r = 0; r < 4; ++r) {
                int row = m0 + wm * 64 + i * 16 + quad * 4 + r;
                int col = n0 + wn * 64 + j * 16 + lane15;
                D[(size_t)row * C_ + col] = acc[i][j][r] + Add[(size_t)row * C_ + col];
            }
}

// ---------------- kernel 3: per-head RMSNorm + RoPE (in place on q and k) ----------------
__global__ __launch_bounds__(256) void qknorm_rope(bf16* __restrict__ q, bf16* __restrict__ k) {
    const int bt = blockIdx.x;
    bf16* buf = blockIdx.y ? k : q;
    const int w = threadIdx.x >> 6, L = threadIdx.x & 63;
    const int t = bt & (T_ - 1);
    // inv_freq = 10000^(-L/64) in high precision; angle fp32 (matches np fp32 tables to ~1ulp)
    float inv = (float)exp2(-(double)L * 0.20762050593046006);
    float ang = (float)t * inv;
    float s, c;
    sincosf(ang, &s, &c);
#pragma unroll
    for (int hh = 0; hh < 4; ++hh) {
        int h = w * 4 + hh;
        bf16* p = buf + (size_t)bt * C_ + h * DH_;
        float x1 = bf2f(p[L]), x2 = bf2f(p[L + 64]);
        float ss = x1 * x1 + x2 * x2;
#pragma unroll
        for (int m = 32; m; m >>= 1) ss += __shfl_xor(ss, m, 64);
        float sc = rsqrtf(ss * (1.0f / (float)DH_) + 1.1920929e-07f);
        float y1 = (x1 * c + x2 * s) * sc;
        float y2 = (x2 * c - x1 * s) * sc;
        p[L]      = f2bf(y1);
        p[L + 64] = f2bf(y2);
    }
}

// ---------------- kernel 4: causal flash attention (R1/R2 version, measured 237us) ----------------
__global__ __launch_bounds__(256, 2)
void attn_fwd(const bf16* __restrict__ q, const bf16* __restrict__ k,
              const bf16* __restrict__ vt, bf16* __restrict__ y) {
    __shared__ __align__(16) bf16 sKP[128 * 128];  // K tile, later reused for P
    __shared__ __align__(16) bf16 sV[128 * 128];   // Vt tile [dh][kr]
    const int qt = blockIdx.x, bh = blockIdx.y;
    const int b = bh >> 4, h = bh & 15;
    const int tid = threadIdx.x;
    const int w = tid >> 6, L = tid & 63;
    const int lane15 = L & 15, quad = L >> 4;
    const float SCALE = 0.08838834764831845f;      // 1/sqrt(128)

    // Q fragments in registers: B-operand layout B[k=d][n=qrow]
    bf16x8 qf[2][4];
#pragma unroll
    for (int nt = 0; nt < 2; ++nt)
#pragma unroll
        for (int ks = 0; ks < 4; ++ks) {
            int qrow = qt * 128 + w * 32 + nt * 16 + lane15;
            qf[nt][ks] = *(const bf16x8*)(q + ((size_t)(b * T_ + qrow)) * C_ + h * DH_ + ks * 32 + quad * 8);
        }

    f32x4 o[2][8] = {};
    float m_i[2] = {-__builtin_inff(), -__builtin_inff()};
    float l_i[2] = {0.f, 0.f};

    for (int j = 0; j <= qt; ++j) {
        __syncthreads();   // prior iteration's P/V reads done
        {
            const bf16* kb = k  + ((size_t)(b * T_ + j * 128)) * C_ + h * DH_;
            const bf16* vb = vt + ((size_t)bh * DH_) * T_ + j * 128;
#pragma unroll
            for (int it = 0; it < 8; ++it) {
                int slot = it * 256 + tid;
                int row = slot >> 4;
                int ch = slot & 15;
                bf16x8 kv = *(const bf16x8*)(kb + (size_t)row * C_ + ch * 8);
                bf16x8 vv = *(const bf16x8*)(vb + (size_t)row * T_ + ch * 8);
                *(bf16x8*)(sKP + row * 128 + swz8(row, ch * 8)) = kv;
                *(bf16x8*)(sV  + row * 128 + swz8(row, ch * 8)) = vv;
            }
        }
        __syncthreads();

        // S^T: rows = kr (8 m-tiles), cols = qrow (2 n-tiles)
        f32x4 sc[8][2] = {};
#pragma unroll
        for (int ks = 0; ks < 4; ++ks)
#pragma unroll
            for (int mt = 0; mt < 8; ++mt) {
                int ar = mt * 16 + lane15;
                bf16x8 a = *(const bf16x8*)(sKP + ar * 128 + swz8(ar, (ks * 4 + quad) * 8));
                sc[mt][0] = __builtin_amdgcn_mfma_f32_16x16x32_bf16(a, qf[0][ks], sc[mt][0], 0, 0, 0);
                sc[mt][1] = __builtin_amdgcn_mfma_f32_16x16x32_bf16(a, qf[1][ks], sc[mt][1], 0, 0, 0);
            }

        // scale + causal mask + online softmax (stats per qrow = lane&15)
        float alpha[2];
#pragma unroll
        for (int nt = 0; nt < 2; ++nt) {
            const int qr = qt * 128 + w * 32 + nt * 16 + lane15;
            float mx = -__builtin_inff();
#pragma unroll
            for (int mt = 0; mt < 8; ++mt)
#pragma unroll
                for (int r = 0; r < 4; ++r) {
                    float v = sc[mt][nt][r] * SCALE;
                    if (j == qt) {
                        int kr = j * 128 + mt * 16 + quad * 4 + r;
                        if (kr > qr) v = -__builtin_inff();
                    }
                    sc[mt][nt][r] = v;
                    mx = fmaxf(mx, v);
                }
            mx = fmaxf(mx, __shfl_xor(mx, 16));
            mx = fmaxf(mx, __shfl_xor(mx, 32));
            float mn = fmaxf(m_i[nt], mx);
            alpha[nt] = __expf(m_i[nt] - mn);
            float sum = 0.f;
#pragma unroll
            for (int mt = 0; mt < 8; ++mt)
#pragma unroll
                for (int r = 0; r < 4; ++r) {
                    float p = __expf(sc[mt][nt][r] - mn);
                    sc[mt][nt][r] = p;
                    sum += p;
                }
            sum += __shfl_xor(sum, 16);
            sum += __shfl_xor(sum, 32);
            l_i[nt] = l_i[nt] * alpha[nt] + sum;
            m_i[nt] = mn;
        }

        __syncthreads();   // all waves done reading K region -> safe to overwrite with P

        // write P (bf16) into sKP in A-operand layout [qrow][kr], swizzled, b64 packed
#pragma unroll
        for (int mt = 0; mt < 8; ++mt)
#pragma unroll
            for (int nt = 0; nt < 2; ++nt) {
                int prow = w * 32 + nt * 16 + lane15;
                int kr0 = mt * 16 + quad * 4;
                int off = prow * 128 + swz8(prow, kr0);
                unsigned int lo = (unsigned int)f2bf(sc[mt][nt][0]) | ((unsigned int)f2bf(sc[mt][nt][1]) << 16);
                unsigned int hi = (unsigned int)f2bf(sc[mt][nt][2]) | ((unsigned int)f2bf(sc[mt][nt][3]) << 16);
                uint2 val; val.x = lo; val.y = hi;
                *(uint2*)(sKP + off) = val;
            }

        // rescale O by alpha (broadcast from stats lane)
#pragma unroll
        for (int mt = 0; mt < 2; ++mt)
#pragma unroll
            for (int r = 0; r < 4; ++r) {
                float av = __shfl(alpha[mt], quad * 4 + r, 64);
#pragma unroll
                for (int d = 0; d < 8; ++d) o[mt][d][r] *= av;
            }

        __syncthreads();   // P visible

        // O += P * V
#pragma unroll
        for (int ks = 0; ks < 4; ++ks) {
            bf16x8 ap[2];
#pragma unroll
            for (int mt = 0; mt < 2; ++mt) {
                int pr = w * 32 + mt * 16 + lane15;
                ap[mt] = *(const bf16x8*)(sKP + pr * 128 + swz8(pr, (ks * 4 + quad) * 8));
            }
#pragma unroll
            for (int d = 0; d < 8; ++d) {
                int vr = d * 16 + lane15;
                bf16x8 bv = *(const bf16x8*)(sV + vr * 128 + swz8(vr, (ks * 4 + quad) * 8));
                o[0][d] = __builtin_amdgcn_mfma_f32_16x16x32_bf16(ap[0], bv, o[0][d], 0, 0, 0);
                o[1][d] = __builtin_amdgcn_mfma_f32_16x16x32_bf16(ap[1], bv, o[1][d], 0, 0, 0);
            }
        }
    }

    // epilogue: divide by l, store y (bf16 scratch for proj GEMM)
    float rl[2] = {1.f / l_i[0], 1.f / l_i[1]};
#pragma unroll
    for (int mt = 0; mt < 2; ++mt)
#pragma unroll
        for (int r = 0; r < 4; ++r) {
            float linv = __shfl(rl[mt], quad * 4 + r, 64);
            int t = qt * 128 + w * 32 + mt * 16 + quad * 4 + r;
#pragma unroll
            for (int d = 0; d < 8; ++d)
                y[((size_t)(b * T_ + t)) * C_ + h * DH_ + d * 16 + lane15] = f2bf(o[mt][d][r] * linv);
        }
}

// ---------------- launch ----------------
// Inputs fp32, OUTPUT FP32 (64 MB). ws = 3 bf16 tensors (96 MB): x, q, vt.
// d_out doubles as scratch: [0,32MB) = kk (bf16 K), [32,56MB) = bf16 wq/wk/wv.
// wproj-bf16 is converted into the dead q region AFTER attn, so the final proj GEMM
// (which overwrites all of d_out with fp32) never races its own weight reads.
extern "C" void kernel_launch(void* const* d_in, const int* in_sizes, int n_in,
                              void* d_out, int out_size, void* d_ws, size_t ws_size,
                              hipStream_t stream) {
    const float* residual = (const float*)d_in[0];
    const float* wq    = (const float*)d_in[1];
    const float* wk    = (const float*)d_in[2];
    const float* wv    = (const float*)d_in[3];
    const float* wproj = (const float*)d_in[4];

    const size_t NE = (size_t)B_ * T_ * C_;   // 16,777,216
    const size_t WE = (size_t)C_ * C_;        // 4,194,304
    bf16* x  = (bf16*)d_ws;
    bf16* q  = x + NE;
    bf16* vt = q + NE;
    bf16* kk = (bf16*)d_out;                  // scratch inside fp32 out buffer
    bf16* wqb = kk + NE;                      // d_out + 32MB
    bf16* wkb = wqb + WE;
    bf16* wvb = wkb + WE;                     // ends at 56MB < 64MB
    bf16* y  = x;                             // x dead after QKV GEMM; reuse for attention output
    bf16* wpb = q;                            // q dead after attn; reuse for bf16 wproj

    const dim3 gemm_grid(MROWS / 128, C_ / 128);   // 64 x 16
    const int wgrid = (int)(WE / (256 * 8));       // 2048 blocks

    w2bf<<<wgrid, 256, 0, stream>>>(wq, wqb);
    w2bf<<<wgrid, 256, 0, stream>>>(wk, wkb);
    w2bf<<<wgrid, 256, 0, stream>>>(wv, wvb);
    rmsnorm_x<<<MROWS, 256, 0, stream>>>(residual, x);
    gemm_qkv<<<gemm_grid, 256, 0, stream>>>(x, wqb, wkb, wvb, q, kk, vt);
    qknorm_rope<<<dim3(MROWS, 2), 256, 0, stream>>>(q, kk);
    attn_fwd<<<dim3(T_ / 128, B_ * H_), 256, 0, stream>>>(q, kk, vt, y);
    w2bf<<<wgrid, 256, 0, stream>>>(wproj, wpb);
    gemm_proj<<<gemm_grid, 256, 0, stream>>>(y, wpb, (float*)d_out, residual);
}